// Round 2
// 689.205 us; speedup vs baseline: 1.0126x; 1.0126x over previous
//
#include <hip/hip_runtime.h>

// CostVolumeLayer: out[b, idx(i,j), y, x] = (1/81) * sum_c x1[b,c,y,x] * x2[b,c,y-i,x-j]
// i,j in [-4,4], idx = (9i+j) mod 81.  x1,x2: (8,192,128,256) fp32; out: (8,81,128,256) fp32.
//
// Banded MFMA (round 1 structure, verified) + round-2 latency fixes + round 3:
//  - Full-chunk prefetch distance: x2(ck+1) issued BEFORE barrier 2 (pipe stays fed
//    during the x1 wait); x1(ck+1) issued right after build_A(ck) so next iter's
//    build_A never stalls. Prologue pre-issues both streams for chunk 0.
//  - LDS-staged epilogue: 3 slices of 27 disparity channels staged in s_x2 (27.6KB),
//    then written as full 64B lines (float4). Cuts WRITE_SIZE ~3x (was 4B scatter).
//  - XCD-aware bijective block swizzle (1024 blocks = 8 XCDs x 128): each XCD owns
//    one full batch image in row-major tile order -> halo + misaligned-line refetch
//    hits same-XCD L2 instead of HBM.
// (Round-4 resubmit: round-3 bench died in the container-acquire path with no
//  kernel verdict; kernel re-audited for OOB/barrier-divergence/WAR — clean.)

#define SR     4
#define NDISP  81
#define CH     192
#define HH     128
#define WW     256
#define BB     8
#define TILE   16
#define REGN   24          // TILE + 2*SR
#define KC     32          // channels per chunk
#define NCHUNK 6           // 192/32
#define HWSZ   (HH * WW)   // 32768, fits int

typedef __attribute__((ext_vector_type(8))) short  short8;   // 8 bf16 = 4 VGPRs
typedef __attribute__((ext_vector_type(4))) float  float4v;

#if __has_builtin(__builtin_amdgcn_cvt_pk_bf16_f32)
typedef __attribute__((ext_vector_type(2))) __bf16 bf16x2;
__device__ __forceinline__ unsigned packbf(float a, float b) {
    union { bf16x2 v; unsigned u; } c;
    c.v = __builtin_amdgcn_cvt_pk_bf16_f32(a, b);   // lo=a, hi=b
    return c.u;
}
#else
__device__ __forceinline__ unsigned short f2bf(float f) {
    union { float f; unsigned u; } v; v.f = f;
    unsigned r = v.u + 0x7FFFu + ((v.u >> 16) & 1u);
    return (unsigned short)(r >> 16);
}
__device__ __forceinline__ unsigned packbf(float a, float b) {
    return (unsigned)f2bf(a) | ((unsigned)f2bf(b) << 16);
}
#endif

// LDS: per halo pixel p one 64B row (32ch bf16 as 16 dwords); 16B block column
// XOR-swizzled by (p>>1)&3. Pair cp lives in block cp>>2 at dword cp&3.
__device__ __forceinline__ int lds_addr(int p, int cp) {
    return (p << 6) + ((((cp >> 2) ^ ((p >> 1) & 3)) << 4) | ((cp & 3) << 2));
}

__global__ __launch_bounds__(256, 2)
void costvol_kernel(const float* __restrict__ x1, const float* __restrict__ x2,
                    float* __restrict__ out) {
    __shared__ __align__(16) char s_x2[REGN * REGN * KC * 2];   // 36864 B

    const int tid = threadIdx.x;

    // ---- XCD-aware bijective swizzle: flat dispatch id -> spatial tile id ----
    // 1024 blocks, 8 XCDs, 128 blocks/XCD = one full batch image per XCD,
    // row-major tile order (x fastest) for halo L2 reuse.
    const int flat = blockIdx.x + (blockIdx.y << 4) + (blockIdx.z << 7);
    const int swz  = ((flat & 7) << 7) + (flat >> 3);
    const int x0 = (swz & 15) * TILE;
    const int y0 = ((swz >> 4) & 7) * TILE;
    const int bz = swz >> 7;

    const int lane = tid & 63;
    const int wv   = tid >> 6;
    const int wy   = wv >> 1, wx = wv & 1;     // wave quadrant (8x8 px)
    const int quad = lane >> 4;                // k-group (8 ch) / C row group
    const int dy   = (lane & 15) >> 2;         // pixel row within 4x4 M-tile
    const int dx   = lane & 3;

    const float* x1b = x1 + (size_t)bz * CH * HWSZ;
    const float* x2b = x2 + (size_t)bz * CH * HWSZ;

    // ---- x2 staging metadata: 9 units/thread, unit u = tid + 256*s ----
    // decomposition (cp, ry, vx): cp = u/144, ry = (u%144)/6, vx = u%6
    int u_off[9];
    unsigned okmask = 0;
    #pragma unroll
    for (int s = 0; s < 9; ++s) {
        int u = tid + 256 * s;
        int cp = u / 144, rem = u - cp * 144;
        int ry = rem / 6,  vx = rem - ry * 6;
        int gy = y0 - SR + ry, gx = x0 - SR + 4 * vx;
        bool ok = ((unsigned)gy < (unsigned)HH) && ((unsigned)gx < (unsigned)(WW - 3));
        int gyc = min(max(gy, 0), HH - 1);
        int gxc = min(max(gx, 0), WW - 4);
        u_off[s] = 2 * cp * HWSZ + gyc * WW + gxc;   // element offset, chunk-relative
        okmask |= (unsigned)ok << s;
    }
    // x1 pixel offsets for the 4 A-fragments (lane-fixed)
    int pixoff[2][2];
    #pragma unroll
    for (int mty = 0; mty < 2; ++mty)
        #pragma unroll
        for (int mtx = 0; mtx < 2; ++mtx)
            pixoff[mty][mtx] = (y0 + wy * 8 + mty * 4 + dy) * WW
                             + (x0 + wx * 8 + mtx * 4 + dx);

    float4v acc[2][2][9];
    #pragma unroll
    for (int a = 0; a < 2; ++a)
        #pragma unroll
        for (int b = 0; b < 2; ++b)
            #pragma unroll
            for (int o = 0; o < 9; ++o)
                acc[a][b][o] = (float4v){0.f, 0.f, 0.f, 0.f};

    float4v x2A[9], x2B[9];      // in-flight x2 batch (72 VGPRs)
    float   x1s[2][2][8];        // in-flight x1 batch (32 VGPRs)
    short8  A[2][2];

    auto issue_x2 = [&](int ck) {
        const float* p2 = x2b + (size_t)(ck * KC) * HWSZ;
        #pragma unroll
        for (int s = 0; s < 9; ++s) {
            const float* q = p2 + u_off[s];
            x2A[s] = *(const float4v*)q;           // ch 2cp   (always-valid clamped addr)
            x2B[s] = *(const float4v*)(q + HWSZ);  // ch 2cp+1
        }
    };
    auto pack_x2 = [&]() {
        #pragma unroll
        for (int s = 0; s < 9; ++s) {
            int u = tid + 256 * s;
            int cp = u / 144, rem = u - cp * 144;
            int ry = rem / 6,  vx = rem - ry * 6;
            int p = ry * REGN + 4 * vx;
            bool ok = (okmask >> s) & 1u;
            #pragma unroll
            for (int k = 0; k < 4; ++k) {
                unsigned pk = packbf(x2A[s][k], x2B[s][k]);
                pk = ok ? pk : 0u;
                *(unsigned*)(s_x2 + lds_addr(p + k, cp)) = pk;
            }
        }
    };
    auto issue_x1 = [&](int ck) {
        const float* p1 = x1b + (size_t)(ck * KC + quad * 8) * HWSZ;
        #pragma unroll
        for (int mty = 0; mty < 2; ++mty)
            #pragma unroll
            for (int mtx = 0; mtx < 2; ++mtx)
                #pragma unroll
                for (int j = 0; j < 8; ++j)
                    x1s[mty][mtx][j] = p1[(size_t)j * HWSZ + pixoff[mty][mtx]];
    };
    auto build_A = [&]() {
        #pragma unroll
        for (int mty = 0; mty < 2; ++mty)
            #pragma unroll
            for (int mtx = 0; mtx < 2; ++mtx) {
                union { short8 s8; unsigned u4[4]; } af;
                #pragma unroll
                for (int t = 0; t < 4; ++t)
                    af.u4[t] = packbf(x1s[mty][mtx][2 * t], x1s[mty][mtx][2 * t + 1]);
                A[mty][mtx] = af.s8;
            }
    };

    // Prologue: both streams for chunk 0 in flight (x2 first -> counted waits).
    issue_x2(0);
    issue_x1(0);
    for (int ck = 0; ck < NCHUNK; ++ck) {
        // barrier 1: prev chunk's LDS reads already consumed (lgkm waits precede
        // each MFMA), so a bare s_barrier suffices — keeps global loads in flight.
        asm volatile("s_barrier" ::: "memory");
        pack_x2();               // waits x2(ck) only (counted: x1(ck) stays in flight)
        if (ck + 1 < NCHUNK) issue_x2(ck + 1);   // feed the pipe across barrier 2
        // barrier 2: LDS writes must be visible -> lgkmcnt(0), but NOT vmcnt.
        asm volatile("s_waitcnt lgkmcnt(0)\n\ts_barrier" ::: "memory");
        build_A();               // waits x1(ck) — issued a full chunk ago: no stall
        if (ck + 1 < NCHUNK) issue_x1(ck + 1);   // full-chunk prefetch distance
        #pragma unroll
        for (int gy = 0; gy < 4; ++gy) {
            #pragma unroll
            for (int gx = 0; gx < 4; ++gx) {
                int p2 = (wy * 8 + gy * 4 + dy) * REGN + (wx * 8 + gx * 4 + dx);
                short8 Bf = *(const short8*)(s_x2 + (p2 << 6)
                              + ((quad ^ ((p2 >> 1) & 3)) << 4));
                #pragma unroll
                for (int mty = 0; mty < 2; ++mty) {
                    const int oyi = gy - mty;
                    if (oyi < 0 || oyi > 2) continue;
                    #pragma unroll
                    for (int mtx = 0; mtx < 2; ++mtx) {
                        const int oxi = gx - mtx;
                        if (oxi < 0 || oxi > 2) continue;
                        acc[mty][mtx][oyi * 3 + oxi] =
                            __builtin_amdgcn_mfma_f32_16x16x32_bf16(
                                A[mty][mtx], Bf, acc[mty][mtx][oyi * 3 + oxi], 0, 0, 0);
                    }
                }
            }
        }
    }

    // ---- epilogue: band extraction (round-1 math) -> LDS slices -> coalesced writes
    // 81 = 3 slices x 27 idx channels; slice buffer = 27*16*16*4 = 27648 B in s_x2.
    const float scale = 1.0f / 81.0f;
    const int nq = (lane >> 2) & 3;
    const int nx = lane & 3;
    float* s_out = (float*)s_x2;
    for (int sl = 0; sl < 3; ++sl) {
        const int lo = 27 * sl;
        __syncthreads();         // prior LDS use (B-frags / prev slice reads) done
        #pragma unroll
        for (int mty = 0; mty < 2; ++mty) {
            #pragma unroll
            for (int mtx = 0; mtx < 2; ++mtx) {
                const int oyl = wy * 8 + mty * 4 + quad;    // row within tile
                const int oxb = wx * 8 + mtx * 4;           // col base within tile
                #pragma unroll
                for (int oyi = 0; oyi < 3; ++oyi) {
                    const int ip = quad - nq - 4 * (oyi - 1);
                    if ((unsigned)(ip + SR) > 8u) continue;
                    #pragma unroll
                    for (int oxi = 0; oxi < 3; ++oxi) {
                        #pragma unroll
                        for (int reg = 0; reg < 4; ++reg) {
                            const int jp = reg - nx - 4 * (oxi - 1);
                            if ((unsigned)(jp + SR) > 8u) continue;
                            int idx = 9 * ip + jp;
                            if (idx < 0) idx += NDISP;
                            idx -= lo;
                            if ((unsigned)idx < 27u)
                                s_out[(idx << 8) + (oyl << 4) + oxb + reg] =
                                    acc[mty][mtx][oyi * 3 + oxi][reg] * scale;
                        }
                    }
                }
            }
        }
        __syncthreads();
        // cooperative full-line writes: 27*16 rows of 64B; 4 lanes per row.
        for (int k = tid; k < 27 * 64; k += 256) {
            const int idx_l = k >> 6;
            const int rem   = k & 63;
            const int row   = rem >> 2;
            const int c4    = rem & 3;
            float4v v = *(const float4v*)(s_out + 4 * k);
            *(float4v*)(out + ((size_t)(bz * NDISP + lo + idx_l) * HH + y0 + row) * WW
                        + x0 + (c4 << 2)) = v;
        }
    }
}

extern "C" void kernel_launch(void* const* d_in, const int* in_sizes, int n_in,
                              void* d_out, int out_size, void* d_ws, size_t ws_size,
                              hipStream_t stream) {
    const float* x1 = (const float*)d_in[0];
    const float* x2 = (const float*)d_in[1];
    float* out = (float*)d_out;
    (void)in_sizes; (void)n_in; (void)out_size; (void)d_ws; (void)ws_size;

    dim3 grid(WW / TILE, HH / TILE, BB);   // (16, 8, 8) = 1024 blocks
    costvol_kernel<<<grid, 256, 0, stream>>>(x1, x2, out);
}